// Round 1
// baseline (86.835 us; speedup 1.0000x reference)
//
#include <hip/hip_runtime.h>
#include <math.h>

#define MARGIN 0.2f
#define EPSF   1e-16f

// B=512 anchors, one block per anchor; D=128.
__global__ __launch_bounds__(256) void triplet_fused_kernel(
    const float* __restrict__ embs,   // [512,128] f32
    const int*   __restrict__ ids,    // [512] i32
    float*       __restrict__ out,    // [1] f32
    float*       __restrict__ ws)     // ws[0]=sum ws[1]=cnt ws[2](int)=ticket  (pre-zeroed)
{
    const int a    = blockIdx.x;
    const int tid  = threadIdx.x;
    const int lane = tid & 63;
    const int wave = tid >> 6;   // 0..3

    __shared__ float drow[512];     // d[a, j]
    __shared__ int   samef[512];    // id[j] == id[a]
    __shared__ int   plist[512];    // positive indices
    __shared__ int   npos;
    __shared__ float ea[128];
    __shared__ float partS[4];
    __shared__ float partC[4];

    if (tid == 0) npos = 0;
    if (tid < 32) {
        ((float4*)ea)[tid] = ((const float4*)(embs + a * 128))[tid];
    }
    __syncthreads();

    const int id_a = ids[a];

    // ---- hoist this lane's fixed 16-float segment of e_a into registers ----
    const int k0 = (lane & 7) * 16;          // 8 lanes per column, 16 k's each
    float eareg[16];
    #pragma unroll
    for (int i = 0; i < 4; ++i) {
        float4 v = ((const float4*)(ea + k0))[i];
        eareg[4*i+0] = v.x; eareg[4*i+1] = v.y;
        eareg[4*i+2] = v.z; eareg[4*i+3] = v.w;
    }

    // ---- distance row: d[a, col] for all 512 cols ----
    // per iteration: each wave covers 8 columns (8 lanes/column)
    for (int it = 0; it < 16; ++it) {
        const int col = it * 32 + wave * 8 + (lane >> 3);
        const float4* src = (const float4*)(embs + col * 128 + k0);
        float acc = 0.f;
        #pragma unroll
        for (int q = 0; q < 4; ++q) {
            float4 v = src[q];
            float d0 = v.x - eareg[4*q+0];
            float d1 = v.y - eareg[4*q+1];
            float d2 = v.z - eareg[4*q+2];
            float d3 = v.w - eareg[4*q+3];
            acc += d0*d0 + d1*d1 + d2*d2 + d3*d3;
        }
        // reduce across the 8 lanes sharing this column
        acc += __shfl_xor(acc, 1);
        acc += __shfl_xor(acc, 2);
        acc += __shfl_xor(acc, 4);
        if ((lane & 7) == 0) {
            drow[col] = (acc > 0.f) ? sqrtf(acc) : 0.f;
        }
    }

    // ---- same-id flags + compacted positive list ----
    #pragma unroll
    for (int r = 0; r < 2; ++r) {
        const int j = tid + r * 256;
        const int same = (ids[j] == id_a) ? 1 : 0;
        samef[j] = same;
        if (same && j != a) {
            int slot = atomicAdd(&npos, 1);
            plist[slot] = j;
        }
    }
    __syncthreads();

    // ---- triplet accumulation: this thread owns negatives n = tid, tid+256 ----
    const float dn0 = drow[tid];
    const float dn1 = drow[tid + 256];
    const int   ok0 = !samef[tid];
    const int   ok1 = !samef[tid + 256];
    const int   np  = npos;

    float s = 0.f, c = 0.f;
    for (int p = 0; p < np; ++p) {
        const float base = drow[plist[p]] + MARGIN;   // d[a,p] + margin (LDS broadcast)
        if (ok0) {
            float t = base - dn0;
            if (t > 0.f)  s += t;
            if (t > EPSF) c += 1.f;
        }
        if (ok1) {
            float t = base - dn1;
            if (t > 0.f)  s += t;
            if (t > EPSF) c += 1.f;
        }
    }

    // ---- block reduce (64-lane shfl, then 4 wave partials) ----
    #pragma unroll
    for (int off = 1; off < 64; off <<= 1) {
        s += __shfl_xor(s, off);
        c += __shfl_xor(c, off);
    }
    if (lane == 0) { partS[wave] = s; partC[wave] = c; }
    __syncthreads();

    if (tid == 0) {
        const float S = partS[0] + partS[1] + partS[2] + partS[3];
        const float C = partC[0] + partC[1] + partC[2] + partC[3];
        atomicAdd(&ws[0], S);
        atomicAdd(&ws[1], C);
        __threadfence();
        int ticket = atomicAdd((int*)(ws + 2), 1);
        if (ticket == (int)gridDim.x - 1) {
            // device-scope-coherent readback of the totals
            float St = atomicAdd(&ws[0], 0.f);
            float Ct = atomicAdd(&ws[1], 0.f);
            out[0] = St / (Ct + EPSF);
        }
    }
}

extern "C" void kernel_launch(void* const* d_in, const int* in_sizes, int n_in,
                              void* d_out, int out_size, void* d_ws, size_t ws_size,
                              hipStream_t stream) {
    const float* embs = (const float*)d_in[0];
    const int*   ids  = (const int*)d_in[1];
    float*       out  = (float*)d_out;
    float*       ws   = (float*)d_ws;

    // zero sum/cnt/ticket (ws is poisoned 0xAA before every launch)
    hipMemsetAsync(d_ws, 0, 16, stream);

    triplet_fused_kernel<<<512, 256, 0, stream>>>(embs, ids, out, ws);
}

// Round 4
// 65.280 us; speedup vs baseline: 1.3302x; 1.3302x over previous
//
#include <hip/hip_runtime.h>
#include <math.h>

#define MARGIN 0.2f
#define EPSF   1e-16f

// B=512 anchors, D=128. Kernel 1: 256 blocks x 512 threads, 2 anchors/block.
// Writes per-block partial (sum, count) to ws[bid], ws[256+bid] with plain
// stores -- no init of ws required, no global atomics.
__global__ __launch_bounds__(512) void triplet_partial_kernel(
    const float* __restrict__ embs,   // [512,128] f32
    const int*   __restrict__ ids,    // [512] i32
    float*       __restrict__ ws)     // [512] f32 partials
{
    const int bid = blockIdx.x;
    const int tid = threadIdx.x;      // 0..511
    const int g   = tid >> 3;         // 8-lane group id, 0..63
    const int li  = tid & 7;          // lane within group
    const int k0  = li * 16;          // this lane's k-segment
    const int a0  = bid * 2;
    const int a1  = a0 + 1;

    __shared__ float drow0[512];
    __shared__ float drow1[512];
    __shared__ int   sh_ids[512];
    __shared__ int   plist0[64];
    __shared__ int   plist1[64];
    __shared__ int   np0, np1;
    __shared__ float partS[8], partC[8];

    if (tid == 0) { np0 = 0; np1 = 0; }
    sh_ids[tid] = ids[tid];

    // ---- anchor segments -> registers (broadcast loads, L1-served) ----
    float ea0[16], ea1[16];
    {
        const float4* p0 = (const float4*)(embs + a0 * 128 + k0);
        const float4* p1 = (const float4*)(embs + a1 * 128 + k0);
        #pragma unroll
        for (int q = 0; q < 4; ++q) {
            float4 v0 = p0[q];
            ea0[4*q+0] = v0.x; ea0[4*q+1] = v0.y; ea0[4*q+2] = v0.z; ea0[4*q+3] = v0.w;
            float4 v1 = p1[q];
            ea1[4*q+0] = v1.x; ea1[4*q+1] = v1.y; ea1[4*q+2] = v1.z; ea1[4*q+3] = v1.w;
        }
    }
    // anchor norms (reduced across the 8-lane group)
    float na0 = 0.f, na1 = 0.f;
    #pragma unroll
    for (int k = 0; k < 16; ++k) {
        na0 = fmaf(ea0[k], ea0[k], na0);
        na1 = fmaf(ea1[k], ea1[k], na1);
    }
    na0 += __shfl_xor(na0, 1); na0 += __shfl_xor(na0, 2); na0 += __shfl_xor(na0, 4);
    na1 += __shfl_xor(na1, 1); na1 += __shfl_xor(na1, 2); na1 += __shfl_xor(na1, 4);

    __syncthreads();   // sh_ids + np ready

    const int id_a0 = sh_ids[a0];
    const int id_a1 = sh_ids[a1];

    // ---- positive lists (LDS atomic compaction; ~8 entries each) ----
    {
        const int j = tid;
        const int idj = sh_ids[j];
        if (idj == id_a0 && j != a0) { int s = atomicAdd(&np0, 1); plist0[s] = j; }
        if (idj == id_a1 && j != a1) { int s = atomicAdd(&np1, 1); plist1[s] = j; }
    }

    // ---- distance rows via Gram form: d^2 = |a|^2 + |j|^2 - 2 a.j ----
    // 64 groups x 8 cols each
    #pragma unroll
    for (int it = 0; it < 8; ++it) {
        const int col = it * 64 + g;
        const float4* src = (const float4*)(embs + col * 128 + k0);
        float nj = 0.f, dot0 = 0.f, dot1 = 0.f;
        #pragma unroll
        for (int q = 0; q < 4; ++q) {
            float4 v = src[q];
            nj   = fmaf(v.x, v.x, nj);
            nj   = fmaf(v.y, v.y, nj);
            nj   = fmaf(v.z, v.z, nj);
            nj   = fmaf(v.w, v.w, nj);
            dot0 = fmaf(v.x, ea0[4*q+0], dot0);
            dot0 = fmaf(v.y, ea0[4*q+1], dot0);
            dot0 = fmaf(v.z, ea0[4*q+2], dot0);
            dot0 = fmaf(v.w, ea0[4*q+3], dot0);
            dot1 = fmaf(v.x, ea1[4*q+0], dot1);
            dot1 = fmaf(v.y, ea1[4*q+1], dot1);
            dot1 = fmaf(v.z, ea1[4*q+2], dot1);
            dot1 = fmaf(v.w, ea1[4*q+3], dot1);
        }
        nj   += __shfl_xor(nj,   1); nj   += __shfl_xor(nj,   2); nj   += __shfl_xor(nj,   4);
        dot0 += __shfl_xor(dot0, 1); dot0 += __shfl_xor(dot0, 2); dot0 += __shfl_xor(dot0, 4);
        dot1 += __shfl_xor(dot1, 1); dot1 += __shfl_xor(dot1, 2); dot1 += __shfl_xor(dot1, 4);
        if (li == 0) {
            float t0 = na0 + nj - 2.f * dot0;
            float t1 = na1 + nj - 2.f * dot1;
            drow0[col] = (t0 > 0.f) ? sqrtf(t0) : 0.f;
            drow1[col] = (t1 > 0.f) ? sqrtf(t1) : 0.f;
        }
    }
    __syncthreads();

    // ---- triplet accumulation: thread owns negative n = tid ----
    const int   n    = tid;
    const int   idn  = sh_ids[n];
    const float dn0  = drow0[n];
    const float dn1  = drow1[n];
    const int   N0   = np0;
    const int   N1   = np1;

    float s = 0.f, c = 0.f;
    if (idn != id_a0) {
        for (int p = 0; p < N0; ++p) {
            float t = drow0[plist0[p]] + MARGIN - dn0;
            if (t > 0.f)  s += t;
            if (t > EPSF) c += 1.f;
        }
    }
    if (idn != id_a1) {
        for (int p = 0; p < N1; ++p) {
            float t = drow1[plist1[p]] + MARGIN - dn1;
            if (t > 0.f)  s += t;
            if (t > EPSF) c += 1.f;
        }
    }

    // ---- block reduce: 64-lane shfl, then 8 wave partials ----
    #pragma unroll
    for (int off = 1; off < 64; off <<= 1) {
        s += __shfl_xor(s, off);
        c += __shfl_xor(c, off);
    }
    const int wave = tid >> 6;
    if ((tid & 63) == 0) { partS[wave] = s; partC[wave] = c; }
    __syncthreads();

    if (tid == 0) {
        float S = 0.f, C = 0.f;
        #pragma unroll
        for (int w = 0; w < 8; ++w) { S += partS[w]; C += partC[w]; }
        ws[bid]       = S;   // plain stores, distinct slots: no init, no atomics
        ws[256 + bid] = C;
    }
}

// Kernel 2: single block reduces the 256 (S, C) partials.
__global__ __launch_bounds__(256) void triplet_final_kernel(
    const float* __restrict__ ws, float* __restrict__ out)
{
    const int tid = threadIdx.x;
    __shared__ float partS[4], partC[4];

    float s = ws[tid];         // S partial of block tid
    float c = ws[256 + tid];   // C partial of block tid

    #pragma unroll
    for (int off = 1; off < 64; off <<= 1) {
        s += __shfl_xor(s, off);
        c += __shfl_xor(c, off);
    }
    const int wave = tid >> 6;
    if ((tid & 63) == 0) { partS[wave] = s; partC[wave] = c; }
    __syncthreads();

    if (tid == 0) {
        float S = partS[0] + partS[1] + partS[2] + partS[3];
        float C = partC[0] + partC[1] + partC[2] + partC[3];
        out[0] = S / (C + EPSF);
    }
}

extern "C" void kernel_launch(void* const* d_in, const int* in_sizes, int n_in,
                              void* d_out, int out_size, void* d_ws, size_t ws_size,
                              hipStream_t stream) {
    const float* embs = (const float*)d_in[0];
    const int*   ids  = (const int*)d_in[1];
    float*       out  = (float*)d_out;
    float*       ws   = (float*)d_ws;

    triplet_partial_kernel<<<256, 512, 0, stream>>>(embs, ids, ws);
    triplet_final_kernel<<<1, 256, 0, stream>>>(ws, out);
}